// Round 6
// baseline (381.998 us; speedup 1.0000x reference)
//
#include <hip/hip_runtime.h>
#include <hip/hip_bf16.h>

typedef float f32x4 __attribute__((ext_vector_type(4)));
typedef short bf16x8 __attribute__((ext_vector_type(8)));
typedef unsigned short u16;

#define NHEADS 6
#define CIN 192
#define HD 32
#define IMG 256
#define YS_ST 208   // bf16 elems; 416B row stride (16B-aligned, bank-spread for b128 reads)
#define QK_ST 40    // 80B rows
#define VT_ST 72    // 144B rows
#define P_ST  72

__device__ __forceinline__ u16 f2bf(float f) {
    __hip_bfloat16 t = __float2bfloat16(f);
    return *reinterpret_cast<u16*>(&t);
}

// Depthwise 3x3: 4 contiguous channels per iteration -> 36 independent loads
// in flight; packed b64 ys writes.
template<bool CHK>
__device__ __forceinline__ void dwphase(const float* __restrict__ x,
                                        const float* __restrict__ dww,
                                        const float* __restrict__ dwb,
                                        u16 (*ys)[YS_ST],
                                        int b, int r0, int c0, int lane, int wave) {
    const int pi = lane >> 3, pj = lane & 7;
    const int py = r0 + pi, px = c0 + pj;
    for (int cb = wave * 4; cb < CIN; cb += 16) {
        float acc[4];
#pragma unroll
        for (int u = 0; u < 4; ++u) acc[u] = dwb[cb + u];
#pragma unroll
        for (int di = 0; di < 3; ++di) {
            const int yy = py + di - 1;
            const bool yok = !CHK || (unsigned)yy < (unsigned)IMG;
#pragma unroll
            for (int dj = 0; dj < 3; ++dj) {
                const int xx = px + dj - 1;
                const bool ok = !CHK || (yok && (unsigned)xx < (unsigned)IMG);
#pragma unroll
                for (int u = 0; u < 4; ++u) {
                    const float* xp = x + (((size_t)(b * CIN + cb + u)) << 16);
                    const float xv = ok ? xp[yy * IMG + xx] : 0.f;
                    acc[u] += xv * dww[(cb + u) * 9 + di * 3 + dj];
                }
            }
        }
        const unsigned lo = ((unsigned)f2bf(acc[1]) << 16) | f2bf(acc[0]);
        const unsigned hi = ((unsigned)f2bf(acc[3]) << 16) | f2bf(acc[2]);
        uint2 pk; pk.x = lo; pk.y = hi;
        *(uint2*)&ys[lane][cb] = pk;
    }
}

// One block per 8x8 window; 256 threads = 4 waves.
// Weight fragments register-prefetched one head ahead (in flight during
// softmax/PV); A-frags read from LDS per head; swapped QK^T -> lane-local softmax.
__global__ __launch_bounds__(256, 3)
void fused_winattn_mfma(const float* __restrict__ x,
                        const float* __restrict__ dww,
                        const float* __restrict__ dwb,
                        const float* __restrict__ pww,
                        const float* __restrict__ pwb,
                        const u16* __restrict__ wbf,
                        float* __restrict__ out) {
    __shared__ __align__(16) unsigned char smem[50688];
    u16 (*ys)[YS_ST] = (u16 (*)[YS_ST])smem;            // [0, 26624) live all kernel
    u16 (*qs)[QK_ST] = (u16 (*)[QK_ST])(smem + 26624);  // 5120
    u16 (*ks)[QK_ST] = (u16 (*)[QK_ST])(smem + 31744);  // 5120
    u16 (*vt)[VT_ST] = (u16 (*)[VT_ST])(smem + 36864);  // 4608
    u16 (*ps)[P_ST]  = (u16 (*)[P_ST]) (smem + 41472);  // 9216

    // XCD-aware swizzle (4096 blocks, 8 XCDs -> 512 consecutive windows per XCD)
    const int bid = blockIdx.x;
    const int wb  = (bid & 7) * 512 + (bid >> 3);
    const int b   = wb >> 10;
    const int wy  = (wb >> 5) & 31;
    const int wx  = wb & 31;
    const int r0 = wy << 3, c0 = wx << 3;
    const int tid  = threadIdx.x;
    const int lane = tid & 63;
    const int wave = __builtin_amdgcn_readfirstlane(tid >> 6);
    const int l15 = lane & 15;
    const int l4  = lane >> 4;
    const int wr = wave >> 1, wc = wave & 1;
    const int m0 = wave * 16;

    // ---- register-prefetched weight fragments (one head ahead) ----
    bf16x8 wf[3][6];     // [tile: q-ct0, q-ct1, v][kt] ; 4 VGPR each = 72 total
    float biasr[3];
    auto ldfrag = [&](int ocrow, int kt) -> bf16x8 {
        if (wbf) {
            return *(const bf16x8*)(wbf + (size_t)ocrow * CIN + kt * 32 + l4 * 8);
        } else {
            union { u16 u[8]; bf16x8 v; } cv;
            const float* wp = pww + (size_t)ocrow * CIN + kt * 32 + l4 * 8;
#pragma unroll
            for (int i = 0; i < 8; ++i) cv.u[i] = f2bf(wp[i]);
            return cv.v;
        }
    };
    auto loadw = [&](int h) {
        const int rq0 = (wc ? CIN : 0) + h * HD + l15;
        const int rq1 = rq0 + 16;
        const int rv  = 2 * CIN + h * HD + wc * 16 + l15;
#pragma unroll
        for (int kt = 0; kt < 6; ++kt) {
            wf[0][kt] = ldfrag(rq0, kt);
            wf[1][kt] = ldfrag(rq1, kt);
            wf[2][kt] = ldfrag(rv, kt);
        }
        biasr[0] = pwb[rq0]; biasr[1] = pwb[rq1]; biasr[2] = pwb[rv];
    };

    loadw(0);   // in flight during the entire depthwise phase

    // ---------- depthwise 3x3 + bias -> ys bf16 ----------
    if ((unsigned)(wy - 1) < 30u && (unsigned)(wx - 1) < 30u)
        dwphase<false>(x, dww, dwb, ys, b, r0, c0, lane, wave);
    else
        dwphase<true>(x, dww, dwb, ys, b, r0, c0, lane, wave);
    __syncthreads();

    for (int h = 0; h < NHEADS; ++h) {
        // ---- pointwise: A-frags from LDS, weights from prefetched registers ----
        f32x4 accq[2][2];   // [ct][rt]
        f32x4 accv[2];
#pragma unroll
        for (int ct = 0; ct < 2; ++ct) {
            const float bsc = biasr[ct];
            accq[ct][0] = (f32x4){bsc, bsc, bsc, bsc};
            accq[ct][1] = accq[ct][0];
        }
        accv[0] = (f32x4){biasr[2], biasr[2], biasr[2], biasr[2]};
        accv[1] = accv[0];
#pragma unroll
        for (int kt = 0; kt < 6; ++kt) {
            const bf16x8 a0 = *(const bf16x8*)&ys[wr * 32 + l15][kt * 32 + l4 * 8];
            const bf16x8 a1 = *(const bf16x8*)&ys[wr * 32 + 16 + l15][kt * 32 + l4 * 8];
            accq[0][0] = __builtin_amdgcn_mfma_f32_16x16x32_bf16(a0, wf[0][kt], accq[0][0], 0, 0, 0);
            accq[0][1] = __builtin_amdgcn_mfma_f32_16x16x32_bf16(a1, wf[0][kt], accq[0][1], 0, 0, 0);
            accq[1][0] = __builtin_amdgcn_mfma_f32_16x16x32_bf16(a0, wf[1][kt], accq[1][0], 0, 0, 0);
            accq[1][1] = __builtin_amdgcn_mfma_f32_16x16x32_bf16(a1, wf[1][kt], accq[1][1], 0, 0, 0);
            accv[0]    = __builtin_amdgcn_mfma_f32_16x16x32_bf16(a0, wf[2][kt], accv[0], 0, 0, 0);
            accv[1]    = __builtin_amdgcn_mfma_f32_16x16x32_bf16(a1, wf[2][kt], accv[1], 0, 0, 0);
        }
        if (h < NHEADS - 1) loadw(h + 1);   // next head's weights: in flight during rest of this head

        // ---- in-register L2 norms; pre-normalized q/k writes ----
#pragma unroll
        for (int rt = 0; rt < 2; ++rt) {
            f32x4 s;
#pragma unroll
            for (int i = 0; i < 4; ++i)
                s[i] = accq[0][rt][i] * accq[0][rt][i] + accq[1][rt][i] * accq[1][rt][i];
#pragma unroll
            for (int off = 1; off < 16; off <<= 1) {
#pragma unroll
                for (int i = 0; i < 4; ++i) s[i] += __shfl_xor(s[i], off);
            }
#pragma unroll
            for (int i = 0; i < 4; ++i) {
                const float inv = 1.f / fmaxf(sqrtf(s[i]), 1e-12f);
                accq[0][rt][i] *= inv;
                accq[1][rt][i] *= inv;
            }
            const int pxr = wr * 32 + rt * 16 + l4 * 4;
            u16 (*dst)[QK_ST] = wc ? ks : qs;
#pragma unroll
            for (int ct = 0; ct < 2; ++ct)
#pragma unroll
                for (int i = 0; i < 4; ++i)
                    dst[pxr + i][ct * 16 + l15] = f2bf(accq[ct][rt][i]);
        }
        // ---- v: packed b64 transposed writes ----
#pragma unroll
        for (int rt = 0; rt < 2; ++rt) {
            const f32x4 a = accv[rt];
            const int pxr = wr * 32 + rt * 16 + l4 * 4;
            const unsigned lo = ((unsigned)f2bf(a[1]) << 16) | f2bf(a[0]);
            const unsigned hi = ((unsigned)f2bf(a[3]) << 16) | f2bf(a[2]);
            uint2 pk; pk.x = lo; pk.y = hi;
            *(uint2*)&vt[wc * 16 + l15][pxr] = pk;
        }
        __syncthreads();

        // ---- swapped QK^T: S^T = mfma(K, Q) -> lane-local softmax ----
        // lane (l4,l15) reg (ct,i) holds S[k=ct*16+l4*4+i][q=m0+l15]
        const bf16x8 aq = *(const bf16x8*)&qs[m0 + l15][l4 * 8];
        f32x4 st[4];
#pragma unroll
        for (int ct = 0; ct < 4; ++ct) {
            f32x4 z = {0.f, 0.f, 0.f, 0.f};
            const bf16x8 ak = *(const bf16x8*)&ks[ct * 16 + l15][l4 * 8];
            st[ct] = __builtin_amdgcn_mfma_f32_16x16x32_bf16(ak, aq, z, 0, 0, 0);
        }
        float mx = st[0][0];
#pragma unroll
        for (int ct = 0; ct < 4; ++ct)
#pragma unroll
            for (int i = 0; i < 4; ++i) mx = fmaxf(mx, st[ct][i]);
        mx = fmaxf(mx, __shfl_xor(mx, 16));
        mx = fmaxf(mx, __shfl_xor(mx, 32));
        float sum = 0.f;
#pragma unroll
        for (int ct = 0; ct < 4; ++ct)
#pragma unroll
            for (int i = 0; i < 4; ++i) {
                st[ct][i] = __expf(st[ct][i] - mx);
                sum += st[ct][i];
            }
        sum += __shfl_xor(sum, 16);
        sum += __shfl_xor(sum, 32);
        const float rs = 1.f / sum;
        // P[q=m0+l15][k=ct*16+l4*4+i] -> packed b64 (i runs over 4 consecutive k)
#pragma unroll
        for (int ct = 0; ct < 4; ++ct) {
            const unsigned lo = ((unsigned)f2bf(st[ct][1] * rs) << 16) | f2bf(st[ct][0] * rs);
            const unsigned hi = ((unsigned)f2bf(st[ct][3] * rs) << 16) | f2bf(st[ct][2] * rs);
            uint2 pk; pk.x = lo; pk.y = hi;
            *(uint2*)&ps[m0 + l15][ct * 16 + l4 * 4] = pk;
        }
        // ps rows [m0, m0+16) written+read by THIS wave only -> no barrier

        // ---- PV (64x32, K=64) + coalesced store ----
        const bf16x8 ap0 = *(const bf16x8*)&ps[m0 + l15][l4 * 8];
        const bf16x8 ap1 = *(const bf16x8*)&ps[m0 + l15][32 + l4 * 8];
#pragma unroll
        for (int nt = 0; nt < 2; ++nt) {
            f32x4 oa = {0.f, 0.f, 0.f, 0.f};
            const bf16x8 bv0 = *(const bf16x8*)&vt[nt * 16 + l15][l4 * 8];
            const bf16x8 bv1 = *(const bf16x8*)&vt[nt * 16 + l15][32 + l4 * 8];
            oa = __builtin_amdgcn_mfma_f32_16x16x32_bf16(ap0, bv0, oa, 0, 0, 0);
            oa = __builtin_amdgcn_mfma_f32_16x16x32_bf16(ap1, bv1, oa, 0, 0, 0);
            const int dim = h * HD + nt * 16 + l15;
            const int pxr = m0 + l4 * 4;
            const int py = r0 + (pxr >> 3), pxc = c0 + (pxr & 7);
            float* op = out + (((size_t)(b * CIN + dim)) << 16) + py * IMG + pxc;
            *(f32x4*)op = oa;
        }
        __syncthreads();   // qs/ks/vt reusable next head
    }
}

__global__ void cvt_w(const float* __restrict__ w, u16* __restrict__ o, int n) {
    const int i = blockIdx.x * 256 + threadIdx.x;
    if (i < n) o[i] = f2bf(w[i]);
}

extern "C" void kernel_launch(void* const* d_in, const int* in_sizes, int n_in,
                              void* d_out, int out_size, void* d_ws, size_t ws_size,
                              hipStream_t stream) {
    const float* x   = (const float*)d_in[0];
    const float* dww = (const float*)d_in[1];
    const float* dwb = (const float*)d_in[2];
    const float* pww = (const float*)d_in[3];
    const float* pwb = (const float*)d_in[4];
    float* out = (float*)d_out;

    const int nw = 3 * CIN * CIN;
    u16* wbf = nullptr;
    if (ws_size >= (size_t)nw * sizeof(u16)) {
        wbf = (u16*)d_ws;
        hipLaunchKernelGGL(cvt_w, dim3(nw / 256), dim3(256), 0, stream, pww, wbf, nw);
    }
    hipLaunchKernelGGL(fused_winattn_mfma, dim3(4 * 32 * 32), dim3(256), 0, stream,
                       x, dww, dwb, pww, pwb, wbf, out);
}